// Round 3
// baseline (159.338 us; speedup 1.0000x reference)
//
#include <hip/hip_runtime.h>

#define NN   32768
#define HD   128
#define EE   524288
#define GG   256
#define EPG  2048
#define CCd  16
#define LLd  3

typedef short short8 __attribute__((ext_vector_type(8)));   // 8 bf16 = 4 VGPRs
typedef float f32x4 __attribute__((ext_vector_type(4)));

__device__ __forceinline__ unsigned short f2bf(float f) {
  unsigned u = __builtin_bit_cast(unsigned, f);
  return (unsigned short)((u + 0x7FFFu + ((u >> 16) & 1u)) >> 16);  // RNE
}
__device__ __forceinline__ unsigned bfpack(float a, float b) {
  return (unsigned)f2bf(a) | ((unsigned)f2bf(b) << 16);
}

// hTs layout: [f][t] bf16, stride 128 (no pad), 16-B chunks XOR-swizzled so that
// row-major b128 reads (lanes vary f low bits) AND column writes (lanes vary f
// high bits) both spread across bank groups:  phys = (c&8) | ((c ^ f ^ (f>>3)) & 7)
__device__ __forceinline__ int hchunk(int f, int c) {   // c = t>>3 in [0,16)
  return f * 128 + (((c & 8) | ((c ^ f ^ (f >> 3)) & 7)) << 3);
}
__device__ __forceinline__ int hidx(int f, int t) {
  return hchunk(f, t >> 3) + (t & 7);
}

// ---------------- single fully fused kernel ----------------
// grid 256 (1 block/graph), 512 threads (8 waves; wave w owns node rows [16w,16w+16)).
// Absorbs: weight fp32->bf16 conversion (per-block, L2 broadcast), reg_loss
// (distributed, atomicAdd), build-M (LDS atomics), 3 GNN layers (MFMA), pooling,
// final LN + lin, and the cross-block loss combine (ticket + last-block write).
__global__ __launch_bounds__(512) void fused_kernel(
    const float* __restrict__ x,
    const int* __restrict__ esrc, const int* __restrict__ etgt, const int* __restrict__ emask,
    const float* __restrict__ Wn, const float* __restrict__ Wo, const float* __restrict__ Wr,
    const float* __restrict__ bn, const float* __restrict__ bo,
    const float* __restrict__ lng, const float* __restrict__ lnb,
    const float* __restrict__ s,
    const float* __restrict__ flng, const float* __restrict__ flnb,
    const float* __restrict__ linw, const float* __restrict__ bias,
    float* __restrict__ out, float* __restrict__ acc /* [0]=reg [1]=l1 [2]=ticket */) {
  __shared__ __align__(16) unsigned short hTs[128 * 128];  // 32.0 KB  h^T, XOR-swizzled
  __shared__ __align__(16) unsigned short sTs[16 * 136];   //  4.3 KB  s^T [c][t]
  __shared__ __align__(16) unsigned Mlds[2 * 128 * 64];    // 64.0 KB  counts -> bf16 M; pool scratch later
  __shared__ __align__(16) unsigned Wlds[128 * 64];        // 32.0 KB  rotating W (bf16, swizzled)
  __shared__ float finS[128], foutS[128];
  __shared__ float colsumS[CCd], xcs[CCd], axcs[CCd], msk[CCd];

  const int g = blockIdx.x;
  const int tid = threadIdx.x;
  const int wave = tid >> 6;
  const int lane = tid & 63;
  const int m = lane & 15;
  const int q = lane >> 4;
  const int t0 = wave << 4;

  // ---- W fp32 prefetch registers; issue Wn[0] immediately (hides under phases 0-2) ----
  const int wr = tid >> 2, wq = tid & 3, wsw = wr & 7;
  float4 wf[8];
  auto w_load = [&](const float* Wg) {
    const float4* wp = (const float4*)(Wg + wr * 128 + wq * 32);
#pragma unroll
    for (int u = 0; u < 8; ++u) wf[u] = wp[u];
  };
  auto w_store = [&]() {   // convert fp32 -> bf16 and store swizzled 16-B chunks
#pragma unroll
    for (int c = 0; c < 4; ++c) {
      uint4 o;
      o.x = bfpack(wf[c * 2].x, wf[c * 2].y);
      o.y = bfpack(wf[c * 2].z, wf[c * 2].w);
      o.z = bfpack(wf[c * 2 + 1].x, wf[c * 2 + 1].y);
      o.w = bfpack(wf[c * 2 + 1].z, wf[c * 2 + 1].w);
      *(uint4*)&Wlds[wr * 64 + (((wq * 4 + c) ^ wsw) << 2)] = o;
    }
  };
  w_load(Wn);

  // ---- distributed reg_loss: |Wo| (192 floats/block) + |bo| (4 floats, blocks<96) ----
  {
    float rsum = 0.f;
    if (tid < 48) {
      float4 v = ((const float4*)Wo)[g * 48 + tid];
      rsum = fabsf(v.x) + fabsf(v.y) + fabsf(v.z) + fabsf(v.w);
    }
    if (g < 96 && tid == 48) {
      float4 d = *(const float4*)(bo + g * 4);
      rsum = fabsf(d.x) + fabsf(d.y) + fabsf(d.z) + fabsf(d.w);
    }
    if (tid < 64) {
#pragma unroll
      for (int mk = 1; mk < 64; mk <<= 1) rsum += __shfl_xor(rsum, mk, 64);
      if (tid == 0) atomicAdd(&acc[0], rsum);
    }
  }

  // ---- phase 0: zero Mlds + stage x->hTs (swizzled), s->sTs, colsum ----
  {
    uint4* cz = (uint4*)Mlds;   // 4096 uint4
#pragma unroll
    for (int i = 0; i < 8; ++i) cz[i * 512 + tid] = make_uint4(0u, 0u, 0u, 0u);

    const float4* xg = (const float4*)(x + (size_t)g * 16384);
#pragma unroll
    for (int i = 0; i < 8; ++i) {
      int flat = i * 512 + tid;           // 4096 float4s, fully coalesced
      int t = flat >> 5, f0 = (flat & 31) << 2;
      float4 v = xg[flat];
      hTs[hidx(f0 + 0, t)] = f2bf(v.x);
      hTs[hidx(f0 + 1, t)] = f2bf(v.y);
      hTs[hidx(f0 + 2, t)] = f2bf(v.z);
      hTs[hidx(f0 + 3, t)] = f2bf(v.w);
    }
    {
      int t = tid >> 2, c0 = (tid & 3) << 2;
      float4 v = *(const float4*)(s + (size_t)g * 2048 + t * 16 + c0);
      sTs[(c0 + 0) * 136 + t] = f2bf(v.x);
      sTs[(c0 + 1) * 136 + t] = f2bf(v.y);
      sTs[(c0 + 2) * 136 + t] = f2bf(v.z);
      sTs[(c0 + 3) * 136 + t] = f2bf(v.w);
    }
    if (tid < 64) {            // colsum: 4 lanes per column
      int c = tid & 15, qq = tid >> 4;
      float cs = 0.f;
      for (int tt = qq; tt < 128; tt += 4) cs += s[(size_t)g * 2048 + tt * 16 + c];
      cs += __shfl_xor(cs, 16); cs += __shfl_xor(cs, 32);
      if (qq == 0) colsumS[c] = cs;
    }
  }
  __syncthreads();

  // ---- phase 1: edge binning (2048 edges, 4 per thread), swizzled quads ----
  {
    const int e0 = g * EPG;
#pragma unroll
    for (int i = 0; i < 4; ++i) {
      int e = e0 + i * 512 + tid;
      int t = etgt[e] & 127;
      int sl = esrc[e] & 127;
      int dir = (emask[e] != 0) ? 0 : 1;
      atomicAdd(&Mlds[dir * 8192 + t * 64 + (((sl >> 3) ^ (t & 7)) << 2) + ((sl >> 1) & 3)],
                1u << ((sl & 1) * 16));
    }
  }
  __syncthreads();

  // ---- phase 2: in-place count->bf16 (x inv-degree) + fin/fout ----
  {
    const int t = t0 + m;
    const int mm = m & 7;
    unsigned nin = 0, nout = 0;
#pragma unroll
    for (int k4 = 0; k4 < 4; ++k4) {
      int sl = (((q * 4 + k4) ^ mm) & 15) << 2;   // XOR-rotated phys slot order
      uint4 a = *(const uint4*)&Mlds[t * 64 + sl];
      uint4 b = *(const uint4*)&Mlds[8192 + t * 64 + sl];
      nin  += (a.x & 0xffffu) + (a.x >> 16) + (a.y & 0xffffu) + (a.y >> 16)
            + (a.z & 0xffffu) + (a.z >> 16) + (a.w & 0xffffu) + (a.w >> 16);
      nout += (b.x & 0xffffu) + (b.x >> 16) + (b.y & 0xffffu) + (b.y >> 16)
            + (b.z & 0xffffu) + (b.z >> 16) + (b.w & 0xffffu) + (b.w >> 16);
    }
    nin  += __shfl_xor((int)nin, 16);  nin  += __shfl_xor((int)nin, 32);
    nout += __shfl_xor((int)nout, 16); nout += __shfl_xor((int)nout, 32);
    unsigned dg = nin + nout;
    float inv = 1.0f / (float)(dg > 0 ? dg : 1);
    if (q == 0) { finS[t] = (float)nin * inv; foutS[t] = (float)nout * inv; }
#pragma unroll
    for (int d = 0; d < 2; ++d)
#pragma unroll
      for (int k4 = 0; k4 < 4; ++k4) {
        int sl = (((q * 4 + k4) ^ mm) & 15) << 2;
        unsigned* p = &Mlds[d * 8192 + t * 64 + sl];
        uint4 v = *(const uint4*)p;
        uint4 o;
        o.x = bfpack((float)(v.x & 0xffffu) * inv, (float)(v.x >> 16) * inv);
        o.y = bfpack((float)(v.y & 0xffffu) * inv, (float)(v.y >> 16) * inv);
        o.z = bfpack((float)(v.z & 0xffffu) * inv, (float)(v.z >> 16) * inv);
        o.w = bfpack((float)(v.w & 0xffffu) * inv, (float)(v.w >> 16) * inv);
        *(uint4*)p = o;
      }
  }
  __syncthreads();

  // ---- layers ----
  for (int L = 0; L < LLd; ++L) {
    f32x4 pre[8];
#pragma unroll
    for (int ct = 0; ct < 8; ++ct) pre[ct] = (f32x4){0.f, 0.f, 0.f, 0.f};
    f32x4 accT[8];

#pragma unroll
    for (int sg = 0; sg < 2; ++sg) {
      // --- M phase: accT[ft] = (Agg^T)[f-tile][t-slice], B-frags from Mlds ---
#pragma unroll
      for (int ft = 0; ft < 8; ++ft) accT[ft] = (f32x4){0.f, 0.f, 0.f, 0.f};
#pragma unroll
      for (int hf = 0; hf < 2; ++hf)
#pragma unroll
        for (int ksl = 0; ksl < 2; ++ksl) {
          const int ksg = hf * 2 + ksl;
          short8 bfr = *(const short8*)&Mlds[sg * 8192 + (t0 + m) * 64 + (((ksg * 4 + q) ^ (m & 7)) << 2)];
#pragma unroll
          for (int ft = 0; ft < 8; ++ft) {
            short8 afr = *(const short8*)&hTs[hchunk(ft * 16 + m, ksg * 4 + q)];
            accT[ft] = __builtin_amdgcn_mfma_f32_16x16x32_bf16(afr, bfr, accT[ft], 0, 0, 0);
          }
        }
      // rotate W: store current (Wn/Wo), prefetch next (Wo/Wr)
      __syncthreads();   // prior Wlds readers done
      w_store();
      w_load((sg == 0 ? Wo : Wr) + L * 16384);
      __syncthreads();   // Wlds ready
      // --- main phase: pre += Agg * W^T (A via shfl-transpose, B from Wlds) ---
#pragma unroll
      for (int hf = 0; hf < 2; ++hf)
#pragma unroll
        for (int ksl = 0; ksl < 2; ++ksl) {
          const int ksg = hf * 2 + ksl;
          f32x4 lo = accT[2 * ksg], hi = accT[2 * ksg + 1];
          short8 afr;
#pragma unroll
          for (int j = 0; j < 8; ++j) {
            int srcl = ((((q & 1) << 1) + (j >> 2)) << 4) + m;
            float ylo = __shfl(lo[j & 3], srcl, 64);
            float yhi = __shfl(hi[j & 3], srcl, 64);
            afr[j] = (short)f2bf((q >> 1) ? yhi : ylo);
          }
#pragma unroll
          for (int ct = 0; ct < 8; ++ct) {
            short8 bfr = *(const short8*)&Wlds[(ct * 16 + m) * 64 + (((ksg * 4 + q) ^ (m & 7)) << 2)];
            pre[ct] = __builtin_amdgcn_mfma_f32_16x16x32_bf16(afr, bfr, pre[ct], 0, 0, 0);
          }
        }
    }
    // rotate W: store Wr[L], prefetch Wn[L+1] (if any)
    __syncthreads();
    w_store();
    if (L < LLd - 1) w_load(Wn + (L + 1) * 16384);
    __syncthreads();
    // --- Wr segment: A-frags scalar-read from hTs (broadcast-friendly), B from Wlds ---
#pragma unroll
    for (int hf = 0; hf < 2; ++hf)
#pragma unroll
      for (int ksl = 0; ksl < 2; ++ksl) {
        const int ksg = hf * 2 + ksl;
        short8 afr;
#pragma unroll
        for (int j = 0; j < 8; ++j)
          afr[j] = (short)hTs[hidx(ksg * 32 + q * 8 + j, t0 + m)];
#pragma unroll
        for (int ct = 0; ct < 8; ++ct) {
          short8 bfr = *(const short8*)&Wlds[(ct * 16 + m) * 64 + (((ksg * 4 + q) ^ (m & 7)) << 2)];
          pre[ct] = __builtin_amdgcn_mfma_f32_16x16x32_bf16(afr, bfr, pre[ct], 0, 0, 0);
        }
      }
    __syncthreads();   // all hTs reads done before overwrite
    // --- epilogue: bias mix + LN + ReLU -> hTs (own wave's t-columns: race-free) ---
    {
      float bnv[8], bov[8], gv[8], bv[8];
#pragma unroll
      for (int ct = 0; ct < 8; ++ct) {
        int c = L * 128 + ct * 16 + m;
        bnv[ct] = bn[c]; bov[ct] = bo[c]; gv[ct] = lng[c]; bv[ct] = lnb[c];
      }
#pragma unroll
      for (int r = 0; r < 4; ++r) {
        const int tl = q * 4 + r;
        const float fiv = finS[t0 + tl], fov = foutS[t0 + tl];
        float v[8];
        float sum = 0.f;
#pragma unroll
        for (int ct = 0; ct < 8; ++ct) {
          v[ct] = pre[ct][r] + fiv * bnv[ct] + fov * bov[ct];
          sum += v[ct];
        }
        sum += __shfl_xor(sum, 1); sum += __shfl_xor(sum, 2);
        sum += __shfl_xor(sum, 4); sum += __shfl_xor(sum, 8);
        const float mu = sum * (1.0f / 128.0f);
        float sq = 0.f;
#pragma unroll
        for (int ct = 0; ct < 8; ++ct) { float d = v[ct] - mu; sq += d * d; }
        sq += __shfl_xor(sq, 1); sq += __shfl_xor(sq, 2);
        sq += __shfl_xor(sq, 4); sq += __shfl_xor(sq, 8);
        const float rstd = rsqrtf(sq * (1.0f / 128.0f) + 1e-5f);
#pragma unroll
        for (int ct = 0; ct < 8; ++ct) {
          float o = fmaxf((v[ct] - mu) * rstd * gv[ct] + bv[ct], 0.0f);
          hTs[hidx(ct * 16 + m, t0 + tl)] = f2bf(o);
        }
      }
    }
    __syncthreads();
  }

  // ---- pool: pooled[c][fo] = sum_t s[t][c]*h[t][fo]; wave w does fo-tile w ----
  f32x4 pl = (f32x4){0.f, 0.f, 0.f, 0.f};
#pragma unroll
  for (int ks = 0; ks < 4; ++ks) {
    short8 a = *(const short8*)&sTs[m * 136 + ks * 32 + q * 8];
    short8 b = *(const short8*)&hTs[hchunk(wave * 16 + m, ks * 4 + q)];
    pl = __builtin_amdgcn_mfma_f32_16x16x32_bf16(a, b, pl, 0, 0, 0);
  }
  float* pooledS = (float*)Mlds;   // M dead since last M-phase (>=2 barriers ago)
#pragma unroll
  for (int r = 0; r < 4; ++r) pooledS[(q * 4 + r) * 132 + wave * 16 + m] = pl[r];
  __syncthreads();

  // ---- final LN + lin + mask (threads 0..255) ----
  if (tid < 256) {
    const int c = tid >> 4;
    const int j0 = (tid & 15) << 3;
    float v[8];
#pragma unroll
    for (int jj = 0; jj < 8; ++jj) v[jj] = pooledS[c * 132 + j0 + jj];
    float sum = 0.f;
#pragma unroll
    for (int jj = 0; jj < 8; ++jj) sum += v[jj];
#pragma unroll
    for (int mk = 1; mk < 16; mk <<= 1) sum += __shfl_xor(sum, mk, 64);
    float mu = sum * (1.0f / 128.0f);
    float sq = 0.f;
#pragma unroll
    for (int jj = 0; jj < 8; ++jj) { float d = v[jj] - mu; sq += d * d; }
#pragma unroll
    for (int mk = 1; mk < 16; mk <<= 1) sq += __shfl_xor(sq, mk, 64);
    float rstd = rsqrtf(sq * (1.0f / 128.0f) + 1e-5f);
    float dot = 0.f;
#pragma unroll
    for (int jj = 0; jj < 8; ++jj) {
      float nv = (v[jj] - mu) * rstd * flng[j0 + jj] + flnb[j0 + jj];
      dot += nv * linw[j0 + jj];
    }
#pragma unroll
    for (int mk = 1; mk < 16; mk <<= 1) dot += __shfl_xor(dot, mk, 64);
    if ((tid & 15) == 0) {
      float cm = (colsumS[c] > 0.f) ? 1.0f : 0.0f;
      float xcv = dot * cm;
      out[257 + g * CCd + c] = xcv;
      xcs[c] = xcv; axcs[c] = fabsf(xcv); msk[c] = cm;
    }
  }
  __syncthreads();

  // ---- block reduction + cross-block combine (ticket; last block writes losses) ----
  if (tid == 0) {
    float so = 0.f, sa = 0.f, sd = 0.f;
#pragma unroll
    for (int k = 0; k < CCd; ++k) { so += xcs[k]; sa += axcs[k]; sd += msk[k] + 1e-7f; }
    out[g] = so + bias[0];
    atomicAdd(&acc[1], sa / sd);
    __threadfence();
    unsigned tk = atomicAdd((unsigned*)&acc[2], 1u);
    if (tk == GG - 1) {
      float rg = atomicAdd(&acc[0], 0.0f);   // coherent read-back
      float l1 = atomicAdd(&acc[1], 0.0f);
      out[256] = 0.01f * rg + 0.01f * (l1 * (1.0f / GG));
    }
  }
}

extern "C" void kernel_launch(void* const* d_in, const int* in_sizes, int n_in,
                              void* d_out, int out_size, void* d_ws, size_t ws_size,
                              hipStream_t stream) {
  (void)in_sizes; (void)n_in; (void)out_size; (void)ws_size;
  const float* x    = (const float*)d_in[0];
  const int*   ei   = (const int*)d_in[1];
  const int*   mask = (const int*)d_in[2];
  const float* s    = (const float*)d_in[3];
  const float* Wn   = (const float*)d_in[5];
  const float* bn   = (const float*)d_in[6];
  const float* Wo   = (const float*)d_in[7];
  const float* bo   = (const float*)d_in[8];
  const float* Wr   = (const float*)d_in[9];
  const float* lng  = (const float*)d_in[10];
  const float* lnb  = (const float*)d_in[11];
  const float* flng = (const float*)d_in[12];
  const float* flnb = (const float*)d_in[13];
  const float* linw = (const float*)d_in[14];
  const float* bias = (const float*)d_in[15];
  float* out = (float*)d_out;

  float* acc = (float*)d_ws;   // [0]=reg_loss  [1]=l1 sum  [2]=ticket  [3]=pad

  const int* srcA = ei;
  const int* tgtA = ei + EE;

  hipMemsetAsync(acc, 0, 16, stream);
  fused_kernel<<<GG, 512, 0, stream>>>(x, srcA, tgtA, mask, Wn, Wo, Wr, bn, bo,
                                       lng, lnb, s, flng, flnb, linw, bias, out, acc);
}